// Round 1
// baseline (695.504 us; speedup 1.0000x reference)
//
#include <hip/hip_runtime.h>

// Problem constants (match reference): B=4096, T=256, NC=16, NR=32, D=64
static constexpr int T_DIM = 256;
static constexpr int NC_DIM = 16;
static constexpr int D_DIM = 64;

__global__ __launch_bounds__(256) void linear_update_kernel(
    const float* __restrict__ y,
    const float* __restrict__ Km,
    float* __restrict__ out,
    long long nrows)
{
    const int lane = threadIdx.x & 63;
    const int wave = threadIdx.x >> 6;
    const long long row = (long long)blockIdx.x * 4 + wave;  // row = b*T + t
    if (row >= nrows) return;

    const int t = (int)(row & (T_DIM - 1));
    const long long base = row * D_DIM;

    float v;
    if (lane < 2 * NC_DIM) {
        // C_seq part: channels 0..31
        const int c = lane & (NC_DIM - 1);
        const float2 yv = *reinterpret_cast<const float2*>(y + base + 2 * c);
        const float logs  = Km[base + c];
        const float theta = Km[base + NC_DIM + c];
        const float s = expf(logs);
        float sn, cs;
        sincosf(theta, &sn, &cs);
        const float re = s * cs;
        const float im = s * sn;
        // lane <16 -> out0 = y0*re + y1*im ; lane >=16 -> out1 = -y0*im + y1*re
        v = (lane < NC_DIM) ? (yv.x * re + yv.y * im)
                            : (yv.y * re - yv.x * im);
    } else {
        // R_seq part: channels 32..63, depends only on t=0 row of this b
        const int r = lane - 2 * NC_DIM;
        const long long base0 = (row - t) * D_DIM;  // (b, t=0) row
        const float y0 = y[base0 + 2 * NC_DIM + r];
        const float lr = Km[base0 + 2 * NC_DIM + r];
        v = y0 * expf(lr * (float)t);
    }
    out[base + lane] = v;
}

extern "C" void kernel_launch(void* const* d_in, const int* in_sizes, int n_in,
                              void* d_out, int out_size, void* d_ws, size_t ws_size,
                              hipStream_t stream) {
    const float* y  = (const float*)d_in[0];
    const float* Km = (const float*)d_in[1];
    float* out = (float*)d_out;

    const long long nrows = (long long)out_size / D_DIM;  // B*T = 1,048,576
    const int blocks = (int)((nrows + 3) / 4);             // 4 rows (waves) per block
    linear_update_kernel<<<blocks, 256, 0, stream>>>(y, Km, out, nrows);
}